// Round 7
// baseline (375.317 us; speedup 1.0000x reference)
//
#include <hip/hip_runtime.h>
#include <hip/hip_bf16.h>
#include <hip/hip_cooperative_groups.h>

namespace cg = cooperative_groups;

typedef __bf16 bf16_t;
typedef __bf16 bf16x8 __attribute__((ext_vector_type(8)));
typedef __bf16 bf16x4 __attribute__((ext_vector_type(4)));
typedef float f32x4 __attribute__((ext_vector_type(4)));

#define NH 256
#define NF 512
#define NE 16
#define NTOK 32768
#define TT 64
#define EW (NF*NF/2)      // 131072 elems per expert weight (512*256)
#define GRID 256
#define SMEM_BYTES 41472
// smem: P3: W1s 2x16KB @0 | Hs 2x4KB @32768 | tok_s @40960 | gw_s @41216
//       P3 epilogue: Es 32KB @0
//       P1 gate: gws 16KB @0, lcnt @16384 ; P1 transpose: tile 4.2KB @0
//       P2: segb_s/tot @0

// ===========================================================================
// Phase 1: [bid<128] gate (+x->bf16)   [bid>=128] weight transpose+convert
// ===========================================================================
__device__ __forceinline__ void phase1(char* smem, int bid, int tid,
    const float* __restrict__ x, const float* __restrict__ gate_w,
    const float* __restrict__ gate_b, const float* __restrict__ w1,
    const float* __restrict__ w2, bf16_t* __restrict__ xb,
    bf16_t* __restrict__ w1t, bf16_t* __restrict__ w2t,
    int* __restrict__ pick_e, int* __restrict__ pick_r,
    float2* __restrict__ pick_w, int* __restrict__ blockcnt)
{
    if (bid >= 128) {
        // ---- transpose+convert weights ----
        float (*tile)[33] = (float(*)[33])smem;
        int wkr = bid - 128;
        int tx = tid & 31, ty0 = tid >> 5;
        for (int t = wkr; t < 4096; t += 128) {
            int u = t;
            const float* src; int R, C, isw1;
            if (u < 2048) { src = w1; R = NH; C = NF; isw1 = 1; }
            else          { u -= 2048; src = w2; R = NF; C = NH; isw1 = 0; }
            int e = u >> 7, tt = u & 127;
            int tcols = C / 32;
            int tr = (tt / tcols) * 32, tc = (tt % tcols) * 32;
            src += (size_t)e * R * C;
            #pragma unroll
            for (int i = 0; i < 4; i++) {
                int ty = ty0 + i * 8;
                tile[ty][tx] = src[(size_t)(tr + ty) * C + tc + tx];
            }
            __syncthreads();
            #pragma unroll
            for (int i = 0; i < 4; i++) {
                int ty = ty0 + i * 8;
                int drow = tc + ty;      // f for w1, h for w2
                int dcol = tr + tx;      // k for w1, f for w2
                if (isw1) {
                    // w1t: chunk(32f) images; elem (f,k) at ch*8192+fl*256+gs*8+(k&7)
                    int ch = drow >> 5, fl = drow & 31;
                    int g = dcol >> 3;
                    int gs = (g & 24) | ((g ^ fl) & 7);
                    w1t[(size_t)e * EW + ch * 8192 + fl * 256 + gs * 8 + (dcol & 7)]
                        = (bf16_t)tile[tx][ty];
                } else {
                    // w2t: granule-major (f>>3)*2048 + h*8 + (f&7)
                    w2t[(size_t)e * EW + (size_t)(dcol >> 3) * 2048 + drow * 8 + (dcol & 7)]
                        = (bf16_t)tile[tx][ty];
                }
            }
            __syncthreads();
        }
    } else {
        // ---- gate: logits, top-2, softmax(2), LDS histogram ranks ----
        float* gws = (float*)smem;               // [h*16+e], 16 KB
        int* lcnt  = (int*)(smem + 16384);
        for (int i = tid; i < NH * NE; i += 256) gws[i] = gate_w[i];
        if (tid < NE) lcnt[tid] = 0;
        __syncthreads();
        int tok = bid * 256 + tid;
        const float4* xr = (const float4*)(x + (size_t)tok * NH);
        bf16x4* xbr = (bf16x4*)(xb + (size_t)tok * NH);
        float acc[NE];
        #pragma unroll
        for (int e4 = 0; e4 < 4; e4++) {
            float4 b4 = ((const float4*)gate_b)[e4];
            acc[e4*4+0] = b4.x; acc[e4*4+1] = b4.y;
            acc[e4*4+2] = b4.z; acc[e4*4+3] = b4.w;
        }
        #pragma unroll 2
        for (int h4 = 0; h4 < NH / 4; h4++) {
            float4 xv = xr[h4];
            bf16x4 xo;
            xo[0] = (bf16_t)xv.x; xo[1] = (bf16_t)xv.y;
            xo[2] = (bf16_t)xv.z; xo[3] = (bf16_t)xv.w;
            xbr[h4] = xo;
            #pragma unroll
            for (int j = 0; j < 4; j++) {
                float xs = (j == 0) ? xv.x : (j == 1) ? xv.y : (j == 2) ? xv.z : xv.w;
                const float4* g4p = (const float4*)(gws + (h4 * 4 + j) * NE);
                #pragma unroll
                for (int e4 = 0; e4 < 4; e4++) {
                    float4 g4 = g4p[e4];
                    acc[e4*4+0] += xs * g4.x; acc[e4*4+1] += xs * g4.y;
                    acc[e4*4+2] += xs * g4.z; acc[e4*4+3] += xs * g4.w;
                }
            }
        }
        // top-2 (jax.lax.top_k order: strict >, earlier index wins ties)
        float v0 = -1e30f, v1 = -1e30f; int i0 = 0, i1 = 0;
        #pragma unroll
        for (int e = 0; e < NE; e++) {
            float a = acc[e];
            if (a > v0)      { v1 = v0; i1 = i0; v0 = a; i0 = e; }
            else if (a > v1) { v1 = a; i1 = e; }
        }
        float e1 = __expf(v1 - v0);
        float s  = 1.f + e1;
        int r0 = atomicAdd(&lcnt[i0], 1);
        int r1 = atomicAdd(&lcnt[i1], 1);
        pick_e[tok] = i0 | (i1 << 8);
        pick_r[tok] = r0 | (r1 << 16);
        pick_w[tok] = make_float2(1.f / s, e1 / s);
        __syncthreads();
        if (tid < NE) blockcnt[tid * 128 + bid] = lcnt[tid];
    }
}

// ===========================================================================
// Phase 2: [bid<128] scan+scatter picks   [bid==128] per-expert totals
// ===========================================================================
__device__ __forceinline__ void phase2(char* smem, int bid, int tid,
    const int* __restrict__ pick_e, const int* __restrict__ pick_r,
    const float2* __restrict__ pick_w, const int* __restrict__ blockcnt,
    int* __restrict__ bucket_enc, float* __restrict__ bucket_gw,
    int* __restrict__ counts)
{
    if (bid < 128) {
        int* segb_s = (int*)smem;                // [16]
        if (tid < NE) segb_s[tid] = 0;
        __syncthreads();
        {   // exclusive prefix over blocks < bid: thread (e=tid>>4, part=tid&15)
            int e = tid >> 4, part = tid & 15;
            int lo = part * 8, hi = lo + 8; if (hi > bid) hi = bid;
            int p = 0;
            for (int j = lo; j < hi; j++) p += blockcnt[e * 128 + j];
            if (p) atomicAdd(&segb_s[e], p);
        }
        __syncthreads();
        int tok = bid * 256 + tid;
        int pe = pick_e[tok], pr = pick_r[tok];
        float2 w = pick_w[tok];
        int e0 = pe & 255, e1 = (pe >> 8) & 255;
        int p0 = segb_s[e0] + (pr & 0xFFFF);
        int p1 = segb_s[e1] + (pr >> 16);
        bucket_enc[e0 * NTOK + p0] = tok;
        bucket_gw [e0 * NTOK + p0] = w.x;
        bucket_enc[e1 * NTOK + p1] = tok | (1 << 20);
        bucket_gw [e1 * NTOK + p1] = w.y;
    } else if (bid == 128) {
        int* tot = (int*)smem;
        if (tid < NE) tot[tid] = 0;
        __syncthreads();
        int e = tid >> 4, part = tid & 15;
        int p = 0;
        for (int j = part * 8; j < part * 8 + 8; j++) p += blockcnt[e * 128 + j];
        atomicAdd(&tot[e], p);
        __syncthreads();
        if (tid < NE) counts[tid] = tot[tid];
    }
}

// ===========================================================================
// Phase 3: fused expert FFN. bid -> (expert via XCD swizzle, tile worker).
// A-frags in registers; W1 chunk (32f x 256k = 16KB) double-buffered via
// async global_load_lds; Hs (64x32) XOR-swizzled dbuf; 1 barrier per chunk.
// Epilogue stages through LDS for coalesced 128B pairbuf stores.
// ===========================================================================
__device__ __forceinline__ void phase3(char* smem, int bid, int tid,
    const bf16_t* __restrict__ xb, const bf16_t* __restrict__ w1t,
    const float* __restrict__ b1, const bf16_t* __restrict__ w2t,
    const float* __restrict__ b2, const int* __restrict__ counts,
    const int* __restrict__ bucket_enc, const float* __restrict__ bucket_gw,
    bf16_t* __restrict__ pairbuf)
{
    bf16_t* W1s  = (bf16_t*)smem;            // 2 x 8192 elems (32 KB)
    bf16_t* Hs   = (bf16_t*)(smem + 32768);  // 2 x 2048 elems (8 KB)
    int*    tok_s = (int*)(smem + 40960);
    float*  gw_s  = (float*)(smem + 41216);

    const int wave = tid >> 6, lane = tid & 63;
    const int l15 = lane & 15, q = lane >> 4;
    int e     = (bid & 7) * 2 + ((bid >> 3) & 1);   // 2 experts per XCD
    int tile0 = bid >> 4;                           // 0..15
    int n_e = counts[e];
    int mbase = (wave & 1) * 32;   // GEMM1 m-range
    int nh    = wave >> 1;         // GEMM1 f-half of the 32-f chunk
    const bf16_t* w1te = w1t + (size_t)e * EW;
    const bf16_t* w2te = w2t + (size_t)e * EW;

    auto stage_w1 = [&](int ch) {
        const bf16_t* gch = w1te + ch * 8192;
        bf16_t* dstb = W1s + (ch & 1) * 8192;
        #pragma unroll
        for (int i = 0; i < 4; i++) {
            int seg = wave * 4 + i;     // 16 segs x 512 elems (1 KB)
            __builtin_amdgcn_global_load_lds(
                (const __attribute__((address_space(1))) void*)(gch + seg * 512 + lane * 8),
                (__attribute__((address_space(3))) void*)(dstb + seg * 512),
                16, 0, 0);
        }
    };

    int ntiles = (n_e + TT - 1) / TT;
    for (int tile = tile0; tile < ntiles; tile += 16) {
        int tstart = tile * TT;
        __syncthreads();                 // guard LDS reuse across tiles
        if (tid < TT) {
            int slot = tstart + tid;
            if (slot < n_e) {
                tok_s[tid] = bucket_enc[e * NTOK + slot];
                gw_s [tid] = bucket_gw [e * NTOK + slot];
            } else { tok_s[tid] = 0; gw_s[tid] = 0.f; }
        }
        __syncthreads();

        // A-fragments for the whole K=256, in registers (2 m-frags x 8 ks)
        const bf16_t* xr0 = xb + (size_t)(tok_s[mbase + l15] & 0xFFFFF) * NH + q * 8;
        const bf16_t* xr1 = xb + (size_t)(tok_s[mbase + 16 + l15] & 0xFFFFF) * NH + q * 8;
        bf16x8 afr[2][8];
        #pragma unroll
        for (int ks = 0; ks < 8; ks++) {
            afr[0][ks] = *(const bf16x8*)(xr0 + ks * 32);
            afr[1][ks] = *(const bf16x8*)(xr1 + ks * 32);
        }
        stage_w1(0);

        f32x4 oacc[4][4];
        #pragma unroll
        for (int a = 0; a < 4; a++)
            #pragma unroll
            for (int b = 0; b < 4; b++) { f32x4 z = {0.f,0.f,0.f,0.f}; oacc[a][b] = z; }

        auto gemm2 = [&](int ch) {
            const bf16_t* hbuf = Hs + (ch & 1) * 2048;
            bf16x8 af2[4], bf2[4];
            #pragma unroll
            for (int mt = 0; mt < 4; mt++) {
                int row = mt * 16 + l15;
                af2[mt] = *(const bf16x8*)&hbuf[row * 32 + ((q ^ (row & 3)) << 3)];
            }
            #pragma unroll
            for (int nt = 0; nt < 4; nt++) {
                int hh = wave * 64 + nt * 16 + l15;
                bf2[nt] = *(const bf16x8*)&w2te[(size_t)(ch * 4 + q) * 2048 + hh * 8];
            }
            #pragma unroll
            for (int mt = 0; mt < 4; mt++)
                #pragma unroll
                for (int nt = 0; nt < 4; nt++)
                    oacc[mt][nt] = __builtin_amdgcn_mfma_f32_16x16x32_bf16(
                        af2[mt], bf2[nt], oacc[mt][nt], 0, 0, 0);
        };

        __syncthreads();                 // W1s[0] staged (barrier drains DMA)
        #pragma unroll 1
        for (int ch = 0; ch < 16; ch++) {
            if (ch < 15) stage_w1(ch + 1);
            // ---- GEMM1(ch): 32 tok x 16 f, K=256
            const bf16_t* wbuf = W1s + (ch & 1) * 8192;
            int fl = nh * 16 + l15;
            f32x4 hacc[2];
            { f32x4 z = {0.f,0.f,0.f,0.f}; hacc[0] = z; hacc[1] = z; }
            #pragma unroll
            for (int ks = 0; ks < 8; ks++) {
                int g = ks * 4 + q;
                int gs = (g & 24) | ((g ^ fl) & 7);
                bf16x8 bfrag = *(const bf16x8*)&wbuf[fl * 256 + gs * 8];
                hacc[0] = __builtin_amdgcn_mfma_f32_16x16x32_bf16(afr[0][ks], bfrag, hacc[0], 0, 0, 0);
                hacc[1] = __builtin_amdgcn_mfma_f32_16x16x32_bf16(afr[1][ks], bfrag, hacc[1], 0, 0, 0);
            }
            float bv = b1[e * NF + ch * 32 + fl];
            bf16_t* hbuf = Hs + (ch & 1) * 2048;
            int cg = nh * 2 + (l15 >> 3);
            #pragma unroll
            for (int m = 0; m < 2; m++)
                #pragma unroll
                for (int r = 0; r < 4; r++) {
                    int row = mbase + m * 16 + q * 4 + r;
                    float v = hacc[m][r] + bv;
                    v = v > 0.f ? v : 0.f;
                    hbuf[row * 32 + ((cg ^ (row & 3)) << 3) + (l15 & 7)] = (bf16_t)v;
                }
            if (ch > 0) gemm2(ch - 1);
            __syncthreads();             // Hs handoff + DMA drain
        }
        gemm2(15);

        // ---- epilogue: +b2, *gate weight, LDS stage, coalesced stores
        __syncthreads();                 // all waves done with W1s/Hs
        bf16_t* Es = (bf16_t*)smem;      // 64 x 256 bf16 = 32 KB
        #pragma unroll
        for (int nt = 0; nt < 4; nt++) {
            int col = wave * 64 + nt * 16 + l15;
            float b2v = b2[e * NH + col];
            #pragma unroll
            for (int mt = 0; mt < 4; mt++)
                #pragma unroll
                for (int r = 0; r < 4; r++) {
                    int row = mt * 16 + q * 4 + r;
                    Es[row * 256 + col] = (bf16_t)((oacc[mt][nt][r] + b2v) * gw_s[row]);
                }
        }
        __syncthreads();
        {
            int row = tid >> 2, qt = tid & 3;
            if (tstart + row < n_e) {
                int enc = tok_s[row];
                bf16_t* dst = pairbuf
                    + ((size_t)((enc & 0xFFFFF) * 2 + (enc >> 20))) * NH + qt * 64;
                const uint4* srcp = (const uint4*)(Es + row * 256 + qt * 64);
                #pragma unroll
                for (int i = 0; i < 8; i++) ((uint4*)dst)[i] = srcp[i];
            }
        }
    }
}

// ===========================================================================
// Phase 4: residual + LayerNorm (wave-per-token, float4)
// ===========================================================================
__device__ __forceinline__ void phase4(int bid, int tid,
    const float* __restrict__ x, const bf16_t* __restrict__ pairbuf,
    const float* __restrict__ gamma, const float* __restrict__ beta,
    float* __restrict__ out)
{
    const int wave = tid >> 6, lane = tid & 63;
    #pragma unroll 1
    for (int u = bid; u < NTOK / 8; u += GRID) {
        int t0 = u * 8 + wave, t1 = u * 8 + 4 + wave;
        float4 xv0 = ((const float4*)(x + (size_t)t0 * NH))[lane];
        float4 xv1 = ((const float4*)(x + (size_t)t1 * NH))[lane];
        bf16x4 a0 = ((const bf16x4*)(pairbuf + (size_t)(t0 * 2) * NH))[lane];
        bf16x4 b0 = ((const bf16x4*)(pairbuf + (size_t)(t0 * 2 + 1) * NH))[lane];
        bf16x4 a1 = ((const bf16x4*)(pairbuf + (size_t)(t1 * 2) * NH))[lane];
        bf16x4 b1v = ((const bf16x4*)(pairbuf + (size_t)(t1 * 2 + 1) * NH))[lane];
        float4 g4 = ((const float4*)gamma)[lane];
        float4 be4 = ((const float4*)beta)[lane];
        float4 y0, y1;
        y0.x = xv0.x + (float)a0[0] + (float)b0[0];
        y0.y = xv0.y + (float)a0[1] + (float)b0[1];
        y0.z = xv0.z + (float)a0[2] + (float)b0[2];
        y0.w = xv0.w + (float)a0[3] + (float)b0[3];
        y1.x = xv1.x + (float)a1[0] + (float)b1v[0];
        y1.y = xv1.y + (float)a1[1] + (float)b1v[1];
        y1.z = xv1.z + (float)a1[2] + (float)b1v[2];
        y1.w = xv1.w + (float)a1[3] + (float)b1v[3];
        float s0 = y0.x + y0.y + y0.z + y0.w, q0 = y0.x*y0.x + y0.y*y0.y + y0.z*y0.z + y0.w*y0.w;
        float s1 = y1.x + y1.y + y1.z + y1.w, q1 = y1.x*y1.x + y1.y*y1.y + y1.z*y1.z + y1.w*y1.w;
        #pragma unroll
        for (int o = 32; o > 0; o >>= 1) {
            s0 += __shfl_xor(s0, o); q0 += __shfl_xor(q0, o);
            s1 += __shfl_xor(s1, o); q1 += __shfl_xor(q1, o);
        }
        float mu0 = s0 * (1.f / NH), mu1 = s1 * (1.f / NH);
        float r0 = rsqrtf(q0 * (1.f / NH) - mu0 * mu0 + 1e-5f);
        float r1 = rsqrtf(q1 * (1.f / NH) - mu1 * mu1 + 1e-5f);
        float4 o0, o1;
        o0.x = (y0.x - mu0) * r0 * g4.x + be4.x;
        o0.y = (y0.y - mu0) * r0 * g4.y + be4.y;
        o0.z = (y0.z - mu0) * r0 * g4.z + be4.z;
        o0.w = (y0.w - mu0) * r0 * g4.w + be4.w;
        o1.x = (y1.x - mu1) * r1 * g4.x + be4.x;
        o1.y = (y1.y - mu1) * r1 * g4.y + be4.y;
        o1.z = (y1.z - mu1) * r1 * g4.z + be4.z;
        o1.w = (y1.w - mu1) * r1 * g4.w + be4.w;
        ((float4*)(out + (size_t)t0 * NH))[lane] = o0;
        ((float4*)(out + (size_t)t1 * NH))[lane] = o1;
    }
}

// ===========================================================================
#define MEGA_ARGS const float* x, const float* gate_w, const float* gate_b, \
    const float* w1, const float* b1, const float* w2, const float* b2,     \
    const float* gamma, const float* beta, float* out, bf16_t* xb,          \
    bf16_t* w1t, bf16_t* w2t, int* pick_e, int* pick_r, float2* pick_w,     \
    int* blockcnt, int* bucket_enc, float* bucket_gw, int* counts,          \
    bf16_t* pairbuf

__global__ __launch_bounds__(256, 2) void mega_kernel(MEGA_ARGS)
{
    __shared__ __align__(16) char smem[SMEM_BYTES];
    cg::grid_group grid = cg::this_grid();
    int bid = blockIdx.x, tid = threadIdx.x;
    phase1(smem, bid, tid, x, gate_w, gate_b, w1, w2, xb, w1t, w2t,
           pick_e, pick_r, pick_w, blockcnt);
    grid.sync();
    phase2(smem, bid, tid, pick_e, pick_r, pick_w, blockcnt,
           bucket_enc, bucket_gw, counts);
    grid.sync();
    phase3(smem, bid, tid, xb, w1t, b1, w2t, b2, counts,
           bucket_enc, bucket_gw, pairbuf);
    grid.sync();
    phase4(bid, tid, x, pairbuf, gamma, beta, out);
}

// -------- fallback path: same phases as 4 plain launches --------
__global__ __launch_bounds__(256) void p1_kernel(MEGA_ARGS)
{
    __shared__ __align__(16) char smem[SMEM_BYTES];
    phase1(smem, blockIdx.x, threadIdx.x, x, gate_w, gate_b, w1, w2, xb,
           w1t, w2t, pick_e, pick_r, pick_w, blockcnt);
}
__global__ __launch_bounds__(256) void p2_kernel(MEGA_ARGS)
{
    __shared__ __align__(16) char smem[SMEM_BYTES];
    phase2(smem, blockIdx.x, threadIdx.x, pick_e, pick_r, pick_w, blockcnt,
           bucket_enc, bucket_gw, counts);
}
__global__ __launch_bounds__(256, 2) void p3_kernel(MEGA_ARGS)
{
    __shared__ __align__(16) char smem[SMEM_BYTES];
    phase3(smem, blockIdx.x, threadIdx.x, xb, w1t, b1, w2t, b2, counts,
           bucket_enc, bucket_gw, pairbuf);
}
__global__ __launch_bounds__(256) void p4_kernel(MEGA_ARGS)
{
    phase4(blockIdx.x, threadIdx.x, x, pairbuf, gamma, beta, out);
}

// ===========================================================================
extern "C" void kernel_launch(void* const* d_in, const int* in_sizes, int n_in,
                              void* d_out, int out_size, void* d_ws, size_t ws_size,
                              hipStream_t stream) {
    const float* x      = (const float*)d_in[0];
    const float* gate_w = (const float*)d_in[1];
    const float* gate_b = (const float*)d_in[2];
    const float* w1     = (const float*)d_in[3];
    const float* b1     = (const float*)d_in[4];
    const float* w2     = (const float*)d_in[5];
    const float* b2     = (const float*)d_in[6];
    const float* gamma  = (const float*)d_in[7];
    const float* beta   = (const float*)d_in[8];
    float* out = (float*)d_out;

    char* ws = (char*)d_ws;
    const size_t KB = 1024, MB = 1024 * 1024;
    int*    blockcnt   = (int*)ws;                        // 8 KB
    int*    counts     = (int*)(ws + 8 * KB);             // 64 B
    int*    pick_e     = (int*)(ws + 64 * KB);            // 128 KB
    int*    pick_r     = (int*)(ws + 192 * KB);           // 128 KB
    float2* pick_w     = (float2*)(ws + 320 * KB);        // 256 KB
    int*    bucket_enc = (int*)(ws + 1 * MB);             // 2 MB
    float*  bucket_gw  = (float*)(ws + 3 * MB);           // 2 MB
    bf16_t* w1t        = (bf16_t*)(ws + 5 * MB);          // 4 MB
    bf16_t* w2t        = (bf16_t*)(ws + 9 * MB);          // 4 MB
    bf16_t* xb         = (bf16_t*)(ws + 13 * MB);         // 16 MB
    bf16_t* pairbuf    = (bf16_t*)(ws + 29 * MB);         // 32 MB

    void* args[] = {
        (void*)&x, (void*)&gate_w, (void*)&gate_b, (void*)&w1, (void*)&b1,
        (void*)&w2, (void*)&b2, (void*)&gamma, (void*)&beta, (void*)&out,
        (void*)&xb, (void*)&w1t, (void*)&w2t, (void*)&pick_e, (void*)&pick_r,
        (void*)&pick_w, (void*)&blockcnt, (void*)&bucket_enc, (void*)&bucket_gw,
        (void*)&counts, (void*)&pairbuf
    };
    hipError_t err = hipLaunchCooperativeKernel((const void*)mega_kernel,
                                                dim3(GRID), dim3(256), args,
                                                0, stream);
    if (err != hipSuccess) {
        (void)hipGetLastError();   // clear sticky error, use plain pipeline
        p1_kernel<<<256, 256, 0, stream>>>(x, gate_w, gate_b, w1, b1, w2, b2,
            gamma, beta, out, xb, w1t, w2t, pick_e, pick_r, pick_w, blockcnt,
            bucket_enc, bucket_gw, counts, pairbuf);
        p2_kernel<<<129, 256, 0, stream>>>(x, gate_w, gate_b, w1, b1, w2, b2,
            gamma, beta, out, xb, w1t, w2t, pick_e, pick_r, pick_w, blockcnt,
            bucket_enc, bucket_gw, counts, pairbuf);
        p3_kernel<<<256, 256, 0, stream>>>(x, gate_w, gate_b, w1, b1, w2, b2,
            gamma, beta, out, xb, w1t, w2t, pick_e, pick_r, pick_w, blockcnt,
            bucket_enc, bucket_gw, counts, pairbuf);
        p4_kernel<<<256, 256, 0, stream>>>(x, gate_w, gate_b, w1, b1, w2, b2,
            gamma, beta, out, xb, w1t, w2t, pick_e, pick_r, pick_w, blockcnt,
            bucket_enc, bucket_gw, counts, pairbuf);
    }
}